// Round 8
// baseline (1293.418 us; speedup 1.0000x reference)
//
#include <hip/hip_runtime.h>

// V=10000, R=8192, D=1024, B=1024, L=64, M=65536
// R17 = R16 (k_xw/k_mlp = R12-exact) + persistent k_rnn, attempt 2.
// R10's 20us/step stall had two identified causes, both fixed here:
//  (1) breg[32] (Whh B-frags, 128 VGPR) was sunk back into the t-loop by the
//      compiler (VGPR=84 proved it) -> pinned via asm volatile("":"+v"(..)),
//      which makes each frag asm-defined and non-rematerializable.
//      VERIFY next round: k_rnn VGPR_Count ~200 (if ~84, pin failed).
//  (2) one global 256-block barrier (single LLC line, s_sleep convoy).
//      Dependence is row-group-local: h_t[32r..32r+32) is produced and
//      consumed by the SAME 8 blocks -> 32 independent 8-block monotone
//      counters (64B apart, target 8*(t+1)), R10's proven release/relaxed
//      pattern. bx-mapping puts a row-group's blocks on one XCD (perf only;
//      agent-scope release keeps it correct under any mapping).
// Per-step model: MFMA .25 + A-stage 1.1 + 16 intra barriers 1.0 + sync 1-2
// = ~3-4.5us/step -> RNN ~200-290 (was ~490). Predict total ~790-890.
// Fallback if k_rnn >= 450us: revert to 64-launch, do 8-phase k_mlp.
#define D_DIM   1024
#define L_SEQ   64
#define B_BATCH 1024
#define M_NODES 65536
#define R_RULES 8192
#define V_VOCAB 10000
#define NBLK_RNN 256

typedef unsigned short bf16_t;
typedef __attribute__((ext_vector_type(8))) short s8v;   // 8 bf16 (MFMA A/B frag)
typedef __attribute__((ext_vector_type(4))) short s4v;   // 4 bf16
typedef __attribute__((ext_vector_type(4))) float f4v;   // MFMA C/D frag

static __device__ __forceinline__ float bf2f(unsigned short u) {
    union { unsigned int i; float f; } v; v.i = ((unsigned int)u) << 16; return v.f;
}
static __device__ __forceinline__ unsigned short f2bf(float f) {  // RNE
    union { float f; unsigned int i; } v; v.f = f;
    return (unsigned short)((v.i + 0x7FFFu + ((v.i >> 16) & 1u)) >> 16);
}
static __device__ __forceinline__ float fast_tanh(float x) {
    float xc = fminf(fmaxf(x, -15.f), 15.f);
    float t  = __expf(2.f * xc);
    return (t - 1.f) * __builtin_amdgcn_rcpf(t + 1.f);
}

static __device__ __forceinline__ f4v mfma16(s8v a, s8v b, f4v c) {
    return __builtin_amdgcn_mfma_f32_16x16x32_bf16(a, b, c, 0, 0, 0);
}

// ---------------------------------------------------------------------------
__global__ __launch_bounds__(256) void k_cvt_emb(
    const float* __restrict__ emb, bf16_t* __restrict__ embB)
{
    size_t i = ((size_t)blockIdx.x * 256 + threadIdx.x) * 8;
    f4v x0 = *(const f4v*)&emb[i];
    f4v x1 = *(const f4v*)&emb[i + 4];
    s8v o;
    o[0] = (short)f2bf(x0.x); o[1] = (short)f2bf(x0.y);
    o[2] = (short)f2bf(x0.z); o[3] = (short)f2bf(x0.w);
    o[4] = (short)f2bf(x1.x); o[5] = (short)f2bf(x1.y);
    o[6] = (short)f2bf(x1.z); o[7] = (short)f2bf(x1.w);
    *(s8v*)&embB[i] = o;
}

__global__ __launch_bounds__(256) void k_transcvt(
    const float* __restrict__ src, bf16_t* __restrict__ dst, int K, int N)
{
    __shared__ float s[32][33];
    int n0 = blockIdx.x * 32, k0 = blockIdx.y * 32;
    int tx = threadIdx.x, ty = threadIdx.y;  // (32,8)
#pragma unroll
    for (int i = 0; i < 4; ++i)
        s[ty + i * 8][tx] = src[(size_t)(k0 + ty + i * 8) * N + n0 + tx];
    __syncthreads();
#pragma unroll
    for (int i = 0; i < 4; ++i)
        dst[(size_t)(n0 + ty + i * 8) * K + k0 + tx] = f2bf(s[tx][ty + i * 8]);
}

__global__ __launch_bounds__(256) void k_cvt_h0(
    const float* __restrict__ h0, bf16_t* __restrict__ h0b, int* __restrict__ bars)
{
    if (threadIdx.x < 32) bars[threadIdx.x * 16] = 0;   // reset RNN barriers
    for (int u = threadIdx.x; u < D_DIM; u += 256) h0b[u] = f2bf(h0[u]);
}

// ---------------------------------------------------------------------------
// k_xw_mfma: XE[n,:] = bf16(embB[tokens[n],:] @ Wxh + bh)
// 128x128 tile, BK=64, swizzled LDS, depth-1 VGPR prefetch, XCD swizzle.
// (R12 verbatim)
// ---------------------------------------------------------------------------
__global__ __launch_bounds__(256) void k_xw_mfma(
    const int* __restrict__ tokens, const bf16_t* __restrict__ embB,
    const bf16_t* __restrict__ WxhT, const float* __restrict__ bh,
    bf16_t* __restrict__ XE)
{
    __shared__ bf16_t As[128 * 64];            // 16 KB (swizzled 16B slots)
    __shared__ bf16_t Bs[128 * 64];            // 16 KB
    __shared__ float  epi[4][16][68];          // 17.4 KB (per-wave private)

    const int bi  = blockIdx.x;
    const int xcd = bi & 7, j = bi >> 3;
    const int row0 = ((xcd << 6) + (j >> 3)) * 128;   // rowTile in [0,512)
    const int col0 = (j & 7) * 128;                   // colTile in [0,8)

    const int tid = threadIdx.x;
    const int w = tid >> 6, l = tid & 63;
    const int q = l >> 4, t16 = l & 15;
    const int wm = (w >> 1) * 64, wn = (w & 1) * 64;

    const int rr = tid >> 2, c0 = tid & 3;            // staging row / base slot
    const int sw0 = ((c0       ^ (rr & 7)) << 3);     // swizzled slot offsets
    const int sw1 = (((c0 + 4) ^ (rr & 7)) << 3);     // ((rr+64)&7)==(rr&7)

    const bf16_t* arow[2];
#pragma unroll
    for (int r = 0; r < 2; ++r)
        arow[r] = embB + (size_t)tokens[row0 + rr + r * 64] * D_DIM + c0 * 8;
    const bf16_t* brow[2];
#pragma unroll
    for (int r = 0; r < 2; ++r)
        brow[r] = WxhT + (size_t)(col0 + rr + r * 64) * D_DIM + c0 * 8;

    f4v acc[4][4];
#pragma unroll
    for (int i = 0; i < 4; ++i)
#pragma unroll
        for (int jj = 0; jj < 4; ++jj) acc[i][jj] = (f4v)0.f;

    // prefetch chunk 0 (8 x 16B)
    s8v a00 = *(const s8v*)(arow[0]);
    s8v a01 = *(const s8v*)(arow[0] + 32);
    s8v a10 = *(const s8v*)(arow[1]);
    s8v a11 = *(const s8v*)(arow[1] + 32);
    s8v b00 = *(const s8v*)(brow[0]);
    s8v b01 = *(const s8v*)(brow[0] + 32);
    s8v b10 = *(const s8v*)(brow[1]);
    s8v b11 = *(const s8v*)(brow[1] + 32);

    const int r7 = t16 & 7;
    for (int k0 = 0; k0 < D_DIM; k0 += 64) {
        __syncthreads();                       // prev iter frag reads done
        *(s8v*)&As[rr * 64 + sw0]        = a00;
        *(s8v*)&As[rr * 64 + sw1]        = a01;
        *(s8v*)&As[(rr + 64) * 64 + sw0] = a10;
        *(s8v*)&As[(rr + 64) * 64 + sw1] = a11;
        *(s8v*)&Bs[rr * 64 + sw0]        = b00;
        *(s8v*)&Bs[rr * 64 + sw1]        = b01;
        *(s8v*)&Bs[(rr + 64) * 64 + sw0] = b10;
        *(s8v*)&Bs[(rr + 64) * 64 + sw1] = b11;
        int kn = k0 + 64;
        if (kn < D_DIM) {                      // issue next loads
            a00 = *(const s8v*)(arow[0] + kn);
            a01 = *(const s8v*)(arow[0] + kn + 32);
            a10 = *(const s8v*)(arow[1] + kn);
            a11 = *(const s8v*)(arow[1] + kn + 32);
            b00 = *(const s8v*)(brow[0] + kn);
            b01 = *(const s8v*)(brow[0] + kn + 32);
            b10 = *(const s8v*)(brow[1] + kn);
            b11 = *(const s8v*)(brow[1] + kn + 32);
        }
        __syncthreads();
#pragma unroll
        for (int sub = 0; sub < 2; ++sub) {
            const int rsl = (((sub * 4 + q) ^ r7) << 3);
            s8v af[4], bfr[4];
#pragma unroll
            for (int ti = 0; ti < 4; ++ti)
                af[ti] = *(const s8v*)&As[(wm + ti * 16 + t16) * 64 + rsl];
#pragma unroll
            for (int tj = 0; tj < 4; ++tj)
                bfr[tj] = *(const s8v*)&Bs[(wn + tj * 16 + t16) * 64 + rsl];
#pragma unroll
            for (int ti = 0; ti < 4; ++ti)
#pragma unroll
                for (int tj = 0; tj < 4; ++tj)
                    acc[ti][tj] = mfma16(af[ti], bfr[tj], acc[ti][tj]);
        }
    }

    // barrier-free per-wave epilogue (epi[w] wave-private)
    const int lr = l >> 2, c16 = (l & 3) * 16;
    f4v bias[4];
#pragma unroll
    for (int u = 0; u < 4; ++u)
        bias[u] = *(const f4v*)&bh[col0 + wn + c16 + u * 4];
#pragma unroll
    for (int ti = 0; ti < 4; ++ti) {
#pragma unroll
        for (int tj = 0; tj < 4; ++tj)
#pragma unroll
            for (int rg = 0; rg < 4; ++rg)
                epi[w][q * 4 + rg][tj * 16 + t16] = acc[ti][tj][rg];
        s8v o0, o1;
#pragma unroll
        for (int u = 0; u < 8; ++u) {
            o0[u] = (short)f2bf(epi[w][lr][c16 + u]     + bias[u >> 2][u & 3]);
            o1[u] = (short)f2bf(epi[w][lr][c16 + 8 + u] + bias[2 + (u >> 2)][u & 3]);
        }
        size_t orow = (size_t)(row0 + wm + ti * 16 + lr) * D_DIM + col0 + wn + c16;
        *(s8v*)&XE[orow]     = o0;
        *(s8v*)&XE[orow + 8] = o1;
    }
}

// ---------------------------------------------------------------------------
// k_rnn: persistent cooperative kernel, all 64 RNN steps.
// Grid 256 = 32 row-groups (32 batch rows) x 8 col-groups (128 cols).
// 512 threads = 8 waves; wave w owns cols [col0+w*16, +16), all 32 rows.
// Whh B-frags in 128 VGPRs/lane, loaded ONCE, asm-pinned (R10 fix #1).
// Sync: 32 independent 8-block monotone barriers (R10 fix #2).
// A staged per step in XOR-swizzled LDS (R10-verified layout).
// ---------------------------------------------------------------------------
__global__ __launch_bounds__(512, 2) void k_rnn(
    const bf16_t* __restrict__ h0b, const bf16_t* __restrict__ WhhT,
    bf16_t* __restrict__ XE, int* __restrict__ bars)
{
    __shared__ bf16_t As[32 * 128];        // 8 KB, 16B slots XOR-swizzled by row&7
    __shared__ float  epi[8][16][20];      // 10.2 KB (per-wave private)

    const int bx  = blockIdx.x;
    const int rgp = bx & 31;               // row-group; 8 sibling blocks share XCD
    const int cgp = bx >> 5;               // col-group [0,8)
    const int row0 = rgp * 32;
    const int col0 = cgp * 128;

    const int tid = threadIdx.x;
    const int w = tid >> 6, l = tid & 63;
    const int q = l >> 4, t16 = l & 15;

    // ---- B preload: this lane's exact MFMA B-frags for col (col0+w*16+t16),
    // all K=1024 -> 32 s8v = 128 VGPRs. Pinned so the compiler cannot sink.
    s8v breg[32];
    {
        const bf16_t* bp = WhhT + (size_t)(col0 + w * 16 + t16) * D_DIM + q * 8;
#pragma unroll
        for (int ks = 0; ks < 32; ++ks)
            breg[ks] = *(const s8v*)(bp + ks * 32);
#pragma unroll
        for (int ks = 0; ks < 32; ++ks)
            asm volatile("" : "+v"(breg[ks]));
    }

    // ---- A staging geometry (R10-verified): thread (ar, aslot) stages 16B.
    const int ar = tid >> 4, aslot = tid & 15;
    bf16_t* awr = As + ar * 128 + ((aslot ^ (ar & 7)) << 3);
    const int rx = t16 & 7;
    const bf16_t* ard0 = As + t16 * 128;          // rows t16 and 16+t16
    const bf16_t* ard1 = As + (16 + t16) * 128;   // (16+t16)&7 == t16&7

    const size_t xrowA = (size_t)(row0 + ar) * (L_SEQ * D_DIM) + aslot * 8;
    const int lr = l >> 2, c4 = (l & 3) * 4;

    int* bar = bars + rgp * 16;            // 64 B apart per row-group

    for (int t = 0; t < L_SEQ; ++t) {
        const bf16_t* asrc = (t == 0) ? (h0b + aslot * 8)
                                      : (XE + xrowA + (size_t)(t - 1) * D_DIM);
        f4v acc0 = (f4v)0.f, acc1 = (f4v)0.f;
        s8v rA = *(const s8v*)asrc;                    // chunk 0 prefetch
#pragma unroll
        for (int cch = 0; cch < 8; ++cch) {
            __syncthreads();                           // frag reads of prev chunk done
            *(s8v*)awr = rA;
            if (cch < 7) rA = *(const s8v*)(asrc + (cch + 1) * 128);
            __syncthreads();
#pragma unroll
            for (int kk = 0; kk < 4; ++kk) {
                const int sl = ((kk * 4 + q) ^ rx) << 3;
                s8v a0 = *(const s8v*)(ard0 + sl);
                s8v a1 = *(const s8v*)(ard1 + sl);
                acc0 = mfma16(a0, breg[cch * 4 + kk], acc0);
                acc1 = mfma16(a1, breg[cch * 4 + kk], acc1);
            }
        }
        // epilogue: wave-private transpose, add u_t, tanh, store bf16 (in place)
#pragma unroll
        for (int ti = 0; ti < 2; ++ti) {
            f4v a = (ti == 0) ? acc0 : acc1;
#pragma unroll
            for (int rgi = 0; rgi < 4; ++rgi)
                epi[w][q * 4 + rgi][t16] = a[rgi];
            f4v v = *(const f4v*)&epi[w][lr][c4];
            int b = row0 + ti * 16 + lr;
            size_t xi = ((size_t)b * L_SEQ + t) * D_DIM + col0 + w * 16 + c4;
            s4v x = *(const s4v*)&XE[xi];
            s4v o;
#pragma unroll
            for (int u = 0; u < 4; ++u)
                o[u] = (short)f2bf(fast_tanh(bf2f((unsigned short)x[u]) + v[u]));
            *(s4v*)&XE[xi] = o;
        }
        // 8-block row-group barrier (monotone counter; release flushes h_t
        // to coherence point; relaxed spin is safe: reader lines are fresh).
        if (t < L_SEQ - 1) {
            __syncthreads();                 // all waves' stores drained (vmcnt)
            if (tid == 0) {
                __hip_atomic_fetch_add(bar, 1, __ATOMIC_RELEASE, __HIP_MEMORY_SCOPE_AGENT);
                const int target = 8 * (t + 1);
                while (__hip_atomic_load(bar, __ATOMIC_RELAXED, __HIP_MEMORY_SCOPE_AGENT) < target)
                    __builtin_amdgcn_s_sleep(1);
            }
            __syncthreads();
        }
    }
}

// ---------------------------------------------------------------------------
// k_mlp_mfma: h = tanh(concat(XE[i],XE[j]) @ W1 + b1) fused with rule-dot.
// 128x128 tile, K=2048, BK=64, swizzled LDS, depth-1 prefetch, XCD swizzle.
// (R12 verbatim)
// ---------------------------------------------------------------------------
__global__ __launch_bounds__(256) void k_mlp_mfma(
    const int* __restrict__ i_idx, const int* __restrict__ j_idx,
    const bf16_t* __restrict__ XE, const bf16_t* __restrict__ W1T,
    const float* __restrict__ b1, const bf16_t* __restrict__ Wt2,
    const int* __restrict__ r_idx, float* __restrict__ partials)
{
    __shared__ bf16_t As[128 * 64];            // 16 KB
    __shared__ bf16_t Bs[128 * 64];            // 16 KB

    const int bi  = blockIdx.x;
    const int xcd = bi & 7, j = bi >> 3;
    const int rowTile = (xcd << 6) + (j >> 3);        // [0,512)
    const int colTile = j & 7;                        // [0,8)
    const int row0 = rowTile * 128, col0 = colTile * 128;

    const int tid = threadIdx.x;
    const int w = tid >> 6, l = tid & 63;
    const int q = l >> 4, t16 = l & 15;
    const int wm = (w >> 1) * 64, wn = (w & 1) * 64;

    const int rr = tid >> 2, c0 = tid & 3;
    const int sw0 = ((c0       ^ (rr & 7)) << 3);
    const int sw1 = (((c0 + 4) ^ (rr & 7)) << 3);

    const bf16_t* pi[2]; const bf16_t* pj[2];
#pragma unroll
    for (int r = 0; r < 2; ++r) {
        int m = row0 + rr + r * 64;
        pi[r] = XE + (size_t)i_idx[m] * D_DIM + c0 * 8;
        pj[r] = XE + (size_t)j_idx[m] * D_DIM - D_DIM + c0 * 8;  // k in [1024,2048)
    }
    const bf16_t* brow[2];
#pragma unroll
    for (int r = 0; r < 2; ++r)
        brow[r] = W1T + (size_t)(col0 + rr + r * 64) * (2 * D_DIM) + c0 * 8;

    f4v acc[4][4];
#pragma unroll
    for (int i = 0; i < 4; ++i)
#pragma unroll
        for (int jj = 0; jj < 4; ++jj) acc[i][jj] = (f4v)0.f;

    // prefetch chunk 0
    s8v a00 = *(const s8v*)(pi[0]);
    s8v a01 = *(const s8v*)(pi[0] + 32);
    s8v a10 = *(const s8v*)(pi[1]);
    s8v a11 = *(const s8v*)(pi[1] + 32);
    s8v b00 = *(const s8v*)(brow[0]);
    s8v b01 = *(const s8v*)(brow[0] + 32);
    s8v b10 = *(const s8v*)(brow[1]);
    s8v b11 = *(const s8v*)(brow[1] + 32);

    const int r7 = t16 & 7;
    for (int k0 = 0; k0 < 2 * D_DIM; k0 += 64) {
        __syncthreads();
        *(s8v*)&As[rr * 64 + sw0]        = a00;
        *(s8v*)&As[rr * 64 + sw1]        = a01;
        *(s8v*)&As[(rr + 64) * 64 + sw0] = a10;
        *(s8v*)&As[(rr + 64) * 64 + sw1] = a11;
        *(s8v*)&Bs[rr * 64 + sw0]        = b00;
        *(s8v*)&Bs[rr * 64 + sw1]        = b01;
        *(s8v*)&Bs[(rr + 64) * 64 + sw0] = b10;
        *(s8v*)&Bs[(rr + 64) * 64 + sw1] = b11;
        int kn = k0 + 64;
        if (kn < 2 * D_DIM) {
            const bf16_t* A0 = (kn < D_DIM) ? pi[0] : pj[0];
            const bf16_t* A1 = (kn < D_DIM) ? pi[1] : pj[1];
            a00 = *(const s8v*)(A0 + kn);
            a01 = *(const s8v*)(A0 + kn + 32);
            a10 = *(const s8v*)(A1 + kn);
            a11 = *(const s8v*)(A1 + kn + 32);
            b00 = *(const s8v*)(brow[0] + kn);
            b01 = *(const s8v*)(brow[0] + kn + 32);
            b10 = *(const s8v*)(brow[1] + kn);
            b11 = *(const s8v*)(brow[1] + kn + 32);
        }
        __syncthreads();
#pragma unroll
        for (int sub = 0; sub < 2; ++sub) {
            const int rsl = (((sub * 4 + q) ^ r7) << 3);
            s8v af[4], bfr[4];
#pragma unroll
            for (int ti = 0; ti < 4; ++ti)
                af[ti] = *(const s8v*)&As[(wm + ti * 16 + t16) * 64 + rsl];
#pragma unroll
            for (int tj = 0; tj < 4; ++tj)
                bfr[tj] = *(const s8v*)&Bs[(wn + tj * 16 + t16) * 64 + rsl];
#pragma unroll
            for (int ti = 0; ti < 4; ++ti)
#pragma unroll
                for (int tj = 0; tj < 4; ++tj)
                    acc[ti][tj] = mfma16(af[ti], bfr[tj], acc[ti][tj]);
        }
    }

    // fused epilogue in C-layout: fast_tanh, dot with gathered rule row, 16-lane reduce
    const int cb = colTile * 2 + (w & 1);
#pragma unroll
    for (int ti = 0; ti < 4; ++ti) {
#pragma unroll
        for (int rg = 0; rg < 4; ++rg) {
            int m = row0 + wm + ti * 16 + q * 4 + rg;
            int r = r_idx[m];
            const bf16_t* wrow = Wt2 + (size_t)r * D_DIM + col0 + wn + t16;
            float pd = 0.f;
#pragma unroll
            for (int tj = 0; tj < 4; ++tj) {
                int col = col0 + wn + tj * 16 + t16;
                float h = fast_tanh(acc[ti][tj][rg] + b1[col]);
                pd += h * bf2f(wrow[tj * 16]);
            }
            pd += __shfl_xor(pd, 1);
            pd += __shfl_xor(pd, 2);
            pd += __shfl_xor(pd, 4);
            pd += __shfl_xor(pd, 8);
            if (t16 == 0)
                partials[(size_t)cb * M_NODES + m] = pd;
        }
    }
}

// ---------------------------------------------------------------------------
__global__ __launch_bounds__(256) void k_reduce(
    const float* __restrict__ partials, const int* __restrict__ r_idx,
    const float* __restrict__ b2, float* __restrict__ out)
{
    int m = blockIdx.x * 256 + threadIdx.x;
    float s = 0.f;
#pragma unroll
    for (int cb = 0; cb < 16; ++cb)
        s += partials[(size_t)cb * M_NODES + m];
    out[m] = s + b2[r_idx[m]];
}

// ---------------------------------------------------------------------------
extern "C" void kernel_launch(void* const* d_in, const int* in_sizes, int n_in,
                              void* d_out, int out_size, void* d_ws, size_t ws_size,
                              hipStream_t stream) {
    const int*   tokens = (const int*)  d_in[0];
    const int*   i_idx  = (const int*)  d_in[1];
    const int*   j_idx  = (const int*)  d_in[2];
    const int*   r_idx  = (const int*)  d_in[3];
    const float* emb    = (const float*)d_in[4];
    const float* Wxh    = (const float*)d_in[5];
    const float* Whh    = (const float*)d_in[6];
    const float* bh     = (const float*)d_in[7];
    const float* h0     = (const float*)d_in[8];
    const float* W1     = (const float*)d_in[9];
    const float* b1     = (const float*)d_in[10];
    const float* W2     = (const float*)d_in[11];
    const float* b2     = (const float*)d_in[12];
    float* out = (float*)d_out;

    // Workspace (~156 MiB). embB (20 MiB) aliases WhhT/W1T/Wt2 (22 MiB):
    // embB dead after k_xw_mfma; those conversions run after it.
    bf16_t* XE   = (bf16_t*)d_ws;                        // [B*L][D]  128 MiB
    bf16_t* WxhT = XE   + (size_t)M_NODES * D_DIM;       // [D][D]      2 MiB
    bf16_t* WhhT = WxhT + (size_t)D_DIM * D_DIM;         // [D][D]      2 MiB
    bf16_t* W1T  = WhhT + (size_t)D_DIM * D_DIM;         // [D][2D]     4 MiB
    bf16_t* Wt2  = W1T  + (size_t)2 * D_DIM * D_DIM;     // [R][D]     16 MiB
    bf16_t* embB = WhhT;                                 // [V][D]     20 MiB (alias)
    bf16_t* h0b  = Wt2  + (size_t)R_RULES * D_DIM;       // [D] (pad 2048)
    int*    bars = (int*)(h0b + 1024);                   // 32 ctrs, 64B apart (pad)
    float*  par  = (float*)(h0b + 2048);                 // [16][M]     4 MiB

    // Phase 1: emb->bf16, Wxh, h0 (+ zero RNN barrier counters)
    k_cvt_emb<<<V_VOCAB * D_DIM / 2048, 256, 0, stream>>>(emb, embB);
    k_transcvt<<<dim3(D_DIM / 32, D_DIM / 32), dim3(32, 8), 0, stream>>>(Wxh, WxhT, D_DIM, D_DIM);
    k_cvt_h0<<<1, 256, 0, stream>>>(h0, h0b, bars);

    // Phase 2: XE = bf16(embB[tokens] @ Wxh + bh)   (last reader of embB)
    k_xw_mfma<<<4096, 256, 0, stream>>>(tokens, embB, WxhT, bh, XE);

    // Phase 3: remaining weight conversions (overwrite embB region)
    k_transcvt<<<dim3(D_DIM / 32, D_DIM / 32), dim3(32, 8), 0, stream>>>(Whh, WhhT, D_DIM, D_DIM);
    k_transcvt<<<dim3(D_DIM / 32, 2 * D_DIM / 32), dim3(32, 8), 0, stream>>>(W1, W1T, 2 * D_DIM, D_DIM);
    k_transcvt<<<dim3(R_RULES / 32, D_DIM / 32), dim3(32, 8), 0, stream>>>(W2, Wt2, D_DIM, R_RULES);

    // Phase 4: all 64 RNN steps in ONE persistent cooperative kernel
    {
        void* args[] = { (void*)&h0b, (void*)&WhhT, (void*)&XE, (void*)&bars };
        hipLaunchCooperativeKernel((const void*)k_rnn, dim3(NBLK_RNN), dim3(512),
                                   args, 0, stream);
    }

    // Phase 5: MLP + fused rule-dot partials
    k_mlp_mfma<<<4096, 256, 0, stream>>>(
        i_idx, j_idx, XE, W1T, b1, Wt2, r_idx, par);

    // Phase 6: deterministic reduce + b2
    k_reduce<<<M_NODES / 256, 256, 0, stream>>>(par, r_idx, b2, out);
}

// Round 9
// 1159.313 us; speedup vs baseline: 1.1157x; 1.1157x over previous
//
#include <hip/hip_runtime.h>

// V=10000, R=8192, D=1024, B=1024, L=64, M=65536
// R18 = R12 base (1069us) + global_load_lds staging in k_mlp/k_xw.
// R17 post-mortem: persistent k_rnn attempt 2 ALSO showed VGPR=84 -> the
// asm "+v" pin failed to keep the Whh preload in registers; local 8-block
// barriers halved R10's stall (1320->663us) but still lose to the 64-launch
// k_step (~490us). Persistent-RNN line abandoned.
// R18 lever (guide m151): at 128^2 tiles, gl_lds staging = 874 TF vs 646 TF
// reg-staged -- the VGPR round-trip + ds_write pass is the cost. Structure:
// dbuf LDS, ONE raw barrier per chunk: {issue gl_lds next chunk -> ds_read
// frags + MFMA -> s_waitcnt vmcnt(0) -> s_barrier}. Loads get the whole
// compute phase to land; no ds_write phase at all. LDS stays LINEAR (gl_lds
// writes base+lane*16); swizzle moved to PRE-SWIZZLED global source column
// (ss = slot^(row&7)); read XOR unchanged (same involution, rule #21).
// k_xw epi LDS aliased into As (dead after loop, barrier-protected).
// Predict: k_mlp 371->~300 (MfmaUtil 32->40, VALUBusy 19->12), k_xw ->~130,
// total ~970. If k_mlp pinned again -> 2-phase family closed, 8-phase next.
#define D_DIM   1024
#define L_SEQ   64
#define B_BATCH 1024
#define M_NODES 65536
#define R_RULES 8192
#define V_VOCAB 10000

typedef unsigned short bf16_t;
typedef __attribute__((ext_vector_type(8))) short s8v;   // 8 bf16 (MFMA A/B frag)
typedef __attribute__((ext_vector_type(4))) short s4v;   // 4 bf16
typedef __attribute__((ext_vector_type(4))) float f4v;   // MFMA C/D frag

typedef __attribute__((address_space(1))) const void gl_void;
typedef __attribute__((address_space(3))) void lds_void;
static __device__ __forceinline__ void gl16(const void* g, void* l) {
    __builtin_amdgcn_global_load_lds((gl_void*)g, (lds_void*)l, 16, 0, 0);
}

static __device__ __forceinline__ float bf2f(unsigned short u) {
    union { unsigned int i; float f; } v; v.i = ((unsigned int)u) << 16; return v.f;
}
static __device__ __forceinline__ unsigned short f2bf(float f) {  // RNE
    union { float f; unsigned int i; } v; v.f = f;
    return (unsigned short)((v.i + 0x7FFFu + ((v.i >> 16) & 1u)) >> 16);
}
static __device__ __forceinline__ float fast_tanh(float x) {
    float xc = fminf(fmaxf(x, -15.f), 15.f);
    float t  = __expf(2.f * xc);
    return (t - 1.f) * __builtin_amdgcn_rcpf(t + 1.f);
}

static __device__ __forceinline__ f4v mfma16(s8v a, s8v b, f4v c) {
    return __builtin_amdgcn_mfma_f32_16x16x32_bf16(a, b, c, 0, 0, 0);
}

// ---------------------------------------------------------------------------
__global__ __launch_bounds__(256) void k_cvt_emb(
    const float* __restrict__ emb, bf16_t* __restrict__ embB)
{
    size_t i = ((size_t)blockIdx.x * 256 + threadIdx.x) * 8;
    f4v x0 = *(const f4v*)&emb[i];
    f4v x1 = *(const f4v*)&emb[i + 4];
    s8v o;
    o[0] = (short)f2bf(x0.x); o[1] = (short)f2bf(x0.y);
    o[2] = (short)f2bf(x0.z); o[3] = (short)f2bf(x0.w);
    o[4] = (short)f2bf(x1.x); o[5] = (short)f2bf(x1.y);
    o[6] = (short)f2bf(x1.z); o[7] = (short)f2bf(x1.w);
    *(s8v*)&embB[i] = o;
}

__global__ __launch_bounds__(256) void k_transcvt(
    const float* __restrict__ src, bf16_t* __restrict__ dst, int K, int N)
{
    __shared__ float s[32][33];
    int n0 = blockIdx.x * 32, k0 = blockIdx.y * 32;
    int tx = threadIdx.x, ty = threadIdx.y;  // (32,8)
#pragma unroll
    for (int i = 0; i < 4; ++i)
        s[ty + i * 8][tx] = src[(size_t)(k0 + ty + i * 8) * N + n0 + tx];
    __syncthreads();
#pragma unroll
    for (int i = 0; i < 4; ++i)
        dst[(size_t)(n0 + ty + i * 8) * K + k0 + tx] = f2bf(s[tx][ty + i * 8]);
}

__global__ __launch_bounds__(256) void k_cvt_h0(
    const float* __restrict__ h0, bf16_t* __restrict__ h0b)
{
    for (int u = threadIdx.x; u < D_DIM; u += 256) h0b[u] = f2bf(h0[u]);
}

// ---------------------------------------------------------------------------
// k_xw_mfma: XE[n,:] = bf16(embB[tokens[n],:] @ Wxh + bh)
// 128x128 tile, BK=64, dbuf gl_lds staging (linear LDS, pre-swizzled source),
// 1 raw barrier/chunk, XCD swizzle. epi aliased into As after the loop.
// ---------------------------------------------------------------------------
__global__ __launch_bounds__(256) void k_xw_mfma(
    const int* __restrict__ tokens, const bf16_t* __restrict__ embB,
    const bf16_t* __restrict__ WxhT, const float* __restrict__ bh,
    bf16_t* __restrict__ XE)
{
    __shared__ __align__(16) bf16_t As[2][128 * 64];   // 32 KB (linear)
    __shared__ __align__(16) bf16_t Bs[2][128 * 64];   // 32 KB

    const int bi  = blockIdx.x;
    const int xcd = bi & 7, j = bi >> 3;
    const int row0 = ((xcd << 6) + (j >> 3)) * 128;   // rowTile in [0,512)
    const int col0 = (j & 7) * 128;                   // colTile in [0,8)

    const int tid = threadIdx.x;
    const int w = tid >> 6, l = tid & 63;
    const int q = l >> 4, t16 = l & 15;
    const int wm = (w >> 1) * 64, wn = (w & 1) * 64;

    // staging: 8 threads/row, rows (tid>>3)+{0,32,64,96}; source col slot
    // pre-swizzled so LDS stays linear; reads use the same XOR (involution).
    const int srow = tid >> 3, slot = tid & 7;
    const bf16_t* pA[4]; const bf16_t* pB[4];
#pragma unroll
    for (int r = 0; r < 4; ++r) {
        const int row = srow + r * 32;
        const int ss = (slot ^ (row & 7)) << 3;
        pA[r] = embB + (size_t)tokens[row0 + row] * D_DIM + ss;
        pB[r] = WxhT + (size_t)(col0 + row) * D_DIM + ss;
    }

    f4v acc[4][4];
#pragma unroll
    for (int i = 0; i < 4; ++i)
#pragma unroll
        for (int jj = 0; jj < 4; ++jj) acc[i][jj] = (f4v)0.f;

#define XW_STAGE(b_, c_)                                                      \
    {   const int k0s = (c_) * 64;                                            \
        bf16_t* la = &As[b_][tid * 8];                                        \
        bf16_t* lb = &Bs[b_][tid * 8];                                        \
        _Pragma("unroll")                                                     \
        for (int r = 0; r < 4; ++r) {                                         \
            gl16(pA[r] + k0s, la + r * 2048);                                 \
            gl16(pB[r] + k0s, lb + r * 2048);                                 \
        }                                                                     \
    }

    XW_STAGE(0, 0);
    asm volatile("s_waitcnt vmcnt(0)" ::: "memory");
    __builtin_amdgcn_s_barrier();

    const int r7 = t16 & 7;
    for (int c = 0; c < 16; ++c) {
        const int b = c & 1;
        if (c < 15) XW_STAGE(b ^ 1, c + 1);        // issue next chunk (no wait)
#pragma unroll
        for (int sub = 0; sub < 2; ++sub) {
            const int rsl = (((sub * 4 + q) ^ r7) << 3);
            s8v af[4], bfr[4];
#pragma unroll
            for (int ti = 0; ti < 4; ++ti)
                af[ti] = *(const s8v*)&As[b][(wm + ti * 16 + t16) * 64 + rsl];
#pragma unroll
            for (int tj = 0; tj < 4; ++tj)
                bfr[tj] = *(const s8v*)&Bs[b][(wn + tj * 16 + t16) * 64 + rsl];
#pragma unroll
            for (int ti = 0; ti < 4; ++ti)
#pragma unroll
                for (int tj = 0; tj < 4; ++tj)
                    acc[ti][tj] = mfma16(af[ti], bfr[tj], acc[ti][tj]);
        }
        asm volatile("s_waitcnt vmcnt(0)" ::: "memory");   // next chunk landed
        __builtin_amdgcn_s_barrier();
    }
#undef XW_STAGE

    // barrier-free per-wave epilogue; epi aliased into As (dead, post-barrier)
    float (*ep)[68] = (float(*)[68])((float*)As + (size_t)w * 16 * 68);
    const int lr = l >> 2, c16 = (l & 3) * 16;
    f4v bias[4];
#pragma unroll
    for (int u = 0; u < 4; ++u)
        bias[u] = *(const f4v*)&bh[col0 + wn + c16 + u * 4];
#pragma unroll
    for (int ti = 0; ti < 4; ++ti) {
#pragma unroll
        for (int tj = 0; tj < 4; ++tj)
#pragma unroll
            for (int rg = 0; rg < 4; ++rg)
                ep[q * 4 + rg][tj * 16 + t16] = acc[ti][tj][rg];
        s8v o0, o1;
#pragma unroll
        for (int u = 0; u < 8; ++u) {
            o0[u] = (short)f2bf(ep[lr][c16 + u]     + bias[u >> 2][u & 3]);
            o1[u] = (short)f2bf(ep[lr][c16 + 8 + u] + bias[2 + (u >> 2)][u & 3]);
        }
        size_t orow = (size_t)(row0 + wm + ti * 16 + lr) * D_DIM + col0 + wn + c16;
        *(s8v*)&XE[orow]     = o0;
        *(s8v*)&XE[orow + 8] = o1;
    }
}

// ---------------------------------------------------------------------------
// k_step_mfma (x64): y = tanh(XE[b*L+t,:] + h_prev[b,:] @ Whh); XE[..] = bf16(y)
// R12 verbatim (best RNN measured): 64x64 tile, 256 thr, 2x2 quadrants of
// 32x32, BK=64, swizzled LDS, depth-1 reg prefetch.
// ---------------------------------------------------------------------------
__global__ __launch_bounds__(256) void k_step_mfma(
    const bf16_t* __restrict__ Abase, int strideRow,
    const bf16_t* __restrict__ WhhT, bf16_t* __restrict__ XE, int t)
{
    __shared__ bf16_t As[64 * 64];             // 8 KB
    __shared__ bf16_t Bs[64 * 64];             // 8 KB
    __shared__ float  epi[4][16][36];          // 9.2 KB (per-wave private)

    const int tid = threadIdx.x;
    const int w = tid >> 6, l = tid & 63;
    const int q = l >> 4, t16 = l & 15;
    const int wr = w >> 1, wc = w & 1;         // 2x2 quadrants of 32x32
    const int row0 = blockIdx.x * 64, col0 = blockIdx.y * 64;

    const int rr = tid >> 2, c0 = tid & 3;
    const int sw0 = ((c0       ^ (rr & 7)) << 3);
    const int sw1 = (((c0 + 4) ^ (rr & 7)) << 3);

    const bf16_t* asrc = Abase + (size_t)(row0 + rr) * strideRow + c0 * 8;
    const bf16_t* bsrc = WhhT + (size_t)(col0 + rr) * D_DIM + c0 * 8;

    f4v acc[2][2];
#pragma unroll
    for (int i = 0; i < 2; ++i)
#pragma unroll
        for (int jj = 0; jj < 2; ++jj) acc[i][jj] = (f4v)0.f;

    s8v a0 = *(const s8v*)(asrc);
    s8v a1 = *(const s8v*)(asrc + 32);
    s8v b0 = *(const s8v*)(bsrc);
    s8v b1 = *(const s8v*)(bsrc + 32);

    const int r7 = t16 & 7;
    for (int k0 = 0; k0 < D_DIM; k0 += 64) {
        __syncthreads();
        *(s8v*)&As[rr * 64 + sw0] = a0;
        *(s8v*)&As[rr * 64 + sw1] = a1;
        *(s8v*)&Bs[rr * 64 + sw0] = b0;
        *(s8v*)&Bs[rr * 64 + sw1] = b1;
        int kn = k0 + 64;
        if (kn < D_DIM) {
            a0 = *(const s8v*)(asrc + kn);
            a1 = *(const s8v*)(asrc + kn + 32);
            b0 = *(const s8v*)(bsrc + kn);
            b1 = *(const s8v*)(bsrc + kn + 32);
        }
        __syncthreads();
#pragma unroll
        for (int sub = 0; sub < 2; ++sub) {
            const int rsl = (((sub * 4 + q) ^ r7) << 3);
            s8v af[2], bfr[2];
#pragma unroll
            for (int ti = 0; ti < 2; ++ti)
                af[ti] = *(const s8v*)&As[(wr * 32 + ti * 16 + t16) * 64 + rsl];
#pragma unroll
            for (int tj = 0; tj < 2; ++tj)
                bfr[tj] = *(const s8v*)&Bs[(wc * 32 + tj * 16 + t16) * 64 + rsl];
#pragma unroll
            for (int ti = 0; ti < 2; ++ti)
#pragma unroll
                for (int tj = 0; tj < 2; ++tj)
                    acc[ti][tj] = mfma16(af[ti], bfr[tj], acc[ti][tj]);
        }
    }

    // per-wave epilogue, no barriers: transpose 16x32 per ti, add u_t, tanh
    const int lr = l >> 2, cg = l & 3;
#pragma unroll
    for (int ti = 0; ti < 2; ++ti) {
#pragma unroll
        for (int tj = 0; tj < 2; ++tj)
#pragma unroll
            for (int rg = 0; rg < 4; ++rg)
                epi[w][q * 4 + rg][tj * 16 + t16] = acc[ti][tj][rg];
        f4v v0 = *(const f4v*)&epi[w][lr][cg * 8];
        f4v v1 = *(const f4v*)&epi[w][lr][cg * 8 + 4];
        int b = row0 + wr * 32 + ti * 16 + lr;
        size_t xi = ((size_t)b * L_SEQ + t) * D_DIM + col0 + wc * 32 + cg * 8;
        s8v x = *(const s8v*)&XE[xi];
        s8v o;
#pragma unroll
        for (int u = 0; u < 4; ++u) {
            o[u]     = (short)f2bf(fast_tanh(bf2f((unsigned short)x[u])     + v0[u]));
            o[u + 4] = (short)f2bf(fast_tanh(bf2f((unsigned short)x[u + 4]) + v1[u]));
        }
        *(s8v*)&XE[xi] = o;
    }
}

// ---------------------------------------------------------------------------
// k_mlp_mfma: h = tanh(concat(XE[i],XE[j]) @ W1 + b1) fused with rule-dot.
// 128x128 tile, K=2048, BK=64, dbuf gl_lds staging (linear LDS, pre-swizzled
// source), 1 raw barrier/chunk, XCD swizzle.
// ---------------------------------------------------------------------------
__global__ __launch_bounds__(256) void k_mlp_mfma(
    const int* __restrict__ i_idx, const int* __restrict__ j_idx,
    const bf16_t* __restrict__ XE, const bf16_t* __restrict__ W1T,
    const float* __restrict__ b1, const bf16_t* __restrict__ Wt2,
    const int* __restrict__ r_idx, float* __restrict__ partials)
{
    __shared__ __align__(16) bf16_t As[2][128 * 64];   // 32 KB (linear)
    __shared__ __align__(16) bf16_t Bs[2][128 * 64];   // 32 KB

    const int bi  = blockIdx.x;
    const int xcd = bi & 7, j = bi >> 3;
    const int rowTile = (xcd << 6) + (j >> 3);        // [0,512)
    const int colTile = j & 7;                        // [0,8)
    const int row0 = rowTile * 128, col0 = colTile * 128;

    const int tid = threadIdx.x;
    const int w = tid >> 6, l = tid & 63;
    const int q = l >> 4, t16 = l & 15;
    const int wm = (w >> 1) * 64, wn = (w & 1) * 64;

    // staging: 8 threads/row, rows (tid>>3)+{0,32,64,96}, pre-swizzled source.
    const int srow = tid >> 3, slot = tid & 7;
    const bf16_t* pA[4]; const bf16_t* pJ[4]; const bf16_t* pB[4];
#pragma unroll
    for (int r = 0; r < 4; ++r) {
        const int row = srow + r * 32;
        const int m = row0 + row;
        const int ss = (slot ^ (row & 7)) << 3;
        pA[r] = XE + (size_t)i_idx[m] * D_DIM + ss;
        pJ[r] = XE + (size_t)j_idx[m] * D_DIM - D_DIM + ss;  // deref'd only k>=1024
        pB[r] = W1T + (size_t)(col0 + row) * (2 * D_DIM) + ss;
    }

    f4v acc[4][4];
#pragma unroll
    for (int i = 0; i < 4; ++i)
#pragma unroll
        for (int jj = 0; jj < 4; ++jj) acc[i][jj] = (f4v)0.f;

#define MLP_STAGE(b_, c_)                                                     \
    {   const int k0s = (c_) * 64;                                            \
        bf16_t* la = &As[b_][tid * 8];                                        \
        bf16_t* lb = &Bs[b_][tid * 8];                                        \
        _Pragma("unroll")                                                     \
        for (int r = 0; r < 4; ++r) {                                         \
            const bf16_t* ga = ((k0s < D_DIM) ? pA[r] : pJ[r]) + k0s;         \
            gl16(ga, la + r * 2048);                                          \
            gl16(pB[r] + k0s, lb + r * 2048);                                 \
        }                                                                     \
    }

    MLP_STAGE(0, 0);
    asm volatile("s_waitcnt vmcnt(0)" ::: "memory");
    __builtin_amdgcn_s_barrier();

    const int r7 = t16 & 7;
    for (int c = 0; c < 32; ++c) {
        const int b = c & 1;
        if (c < 31) MLP_STAGE(b ^ 1, c + 1);       // issue next chunk (no wait)
#pragma unroll
        for (int sub = 0; sub < 2; ++sub) {
            const int rsl = (((sub * 4 + q) ^ r7) << 3);
            s8v af[4], bfr[4];
#pragma unroll
            for (int ti = 0; ti < 4; ++ti)
                af[ti] = *(const s8v*)&As[b][(wm + ti * 16 + t16) * 64 + rsl];
#pragma unroll
            for (int tj = 0; tj < 4; ++tj)
                bfr[tj] = *(const s8v*)&Bs[b][(wn + tj * 16 + t16) * 64 + rsl];
#pragma unroll
            for (int ti = 0; ti < 4; ++ti)
#pragma unroll
                for (int tj = 0; tj < 4; ++tj)
                    acc[ti][tj] = mfma16(af[ti], bfr[tj], acc[ti][tj]);
        }
        asm volatile("s_waitcnt vmcnt(0)" ::: "memory");   // next chunk landed
        __builtin_amdgcn_s_barrier();
    }
#undef MLP_STAGE

    // fused epilogue in C-layout: fast_tanh, dot with gathered rule row, 16-lane reduce
    const int cb = colTile * 2 + (w & 1);
#pragma unroll
    for (int ti = 0; ti < 4; ++ti) {
#pragma unroll
        for (int rg = 0; rg < 4; ++rg) {
            int m = row0 + wm + ti * 16 + q * 4 + rg;
            int r = r_idx[m];
            const bf16_t* wrow = Wt2 + (size_t)r * D_DIM + col0 + wn + t16;
            float pd = 0.f;
#pragma unroll
            for (int tj = 0; tj < 4; ++tj) {
                int col = col0 + wn + tj * 16 + t16;
                float h = fast_tanh(acc[ti][tj][rg] + b1[col]);
                pd += h * bf2f(wrow[tj * 16]);
            }
            pd += __shfl_xor(pd, 1);
            pd += __shfl_xor(pd, 2);
            pd += __shfl_xor(pd, 4);
            pd += __shfl_xor(pd, 8);
            if (t16 == 0)
                partials[(size_t)cb * M_NODES + m] = pd;
        }
    }
}

// ---------------------------------------------------------------------------
__global__ __launch_bounds__(256) void k_reduce(
    const float* __restrict__ partials, const int* __restrict__ r_idx,
    const float* __restrict__ b2, float* __restrict__ out)
{
    int m = blockIdx.x * 256 + threadIdx.x;
    float s = 0.f;
#pragma unroll
    for (int cb = 0; cb < 16; ++cb)
        s += partials[(size_t)cb * M_NODES + m];
    out[m] = s + b2[r_idx[m]];
}

// ---------------------------------------------------------------------------
extern "C" void kernel_launch(void* const* d_in, const int* in_sizes, int n_in,
                              void* d_out, int out_size, void* d_ws, size_t ws_size,
                              hipStream_t stream) {
    const int*   tokens = (const int*)  d_in[0];
    const int*   i_idx  = (const int*)  d_in[1];
    const int*   j_idx  = (const int*)  d_in[2];
    const int*   r_idx  = (const int*)  d_in[3];
    const float* emb    = (const float*)d_in[4];
    const float* Wxh    = (const float*)d_in[5];
    const float* Whh    = (const float*)d_in[6];
    const float* bh     = (const float*)d_in[7];
    const float* h0     = (const float*)d_in[8];
    const float* W1     = (const float*)d_in[9];
    const float* b1     = (const float*)d_in[10];
    const float* W2     = (const float*)d_in[11];
    const float* b2     = (const float*)d_in[12];
    float* out = (float*)d_out;

    // Workspace (~156 MiB). embB (20 MiB) aliases WhhT/W1T/Wt2 (22 MiB):
    // embB dead after k_xw_mfma; those conversions run after it.
    bf16_t* XE   = (bf16_t*)d_ws;                        // [B*L][D]  128 MiB
    bf16_t* WxhT = XE   + (size_t)M_NODES * D_DIM;       // [D][D]      2 MiB
    bf16_t* WhhT = WxhT + (size_t)D_DIM * D_DIM;         // [D][D]      2 MiB
    bf16_t* W1T  = WhhT + (size_t)D_DIM * D_DIM;         // [D][2D]     4 MiB
    bf16_t* Wt2  = W1T  + (size_t)2 * D_DIM * D_DIM;     // [R][D]     16 MiB
    bf16_t* embB = WhhT;                                 // [V][D]     20 MiB (alias)
    bf16_t* h0b  = Wt2  + (size_t)R_RULES * D_DIM;       // [D] (pad 2048)
    float*  par  = (float*)(h0b + 2048);                 // [16][M]     4 MiB

    // Phase 1: emb->bf16, Wxh, h0
    k_cvt_emb<<<V_VOCAB * D_DIM / 2048, 256, 0, stream>>>(emb, embB);
    k_transcvt<<<dim3(D_DIM / 32, D_DIM / 32), dim3(32, 8), 0, stream>>>(Wxh, WxhT, D_DIM, D_DIM);
    k_cvt_h0<<<1, 256, 0, stream>>>(h0, h0b);

    // Phase 2: XE = bf16(embB[tokens] @ Wxh + bh)   (last reader of embB)
    k_xw_mfma<<<4096, 256, 0, stream>>>(tokens, embB, WxhT, bh, XE);

    // Phase 3: remaining weight conversions (overwrite embB region)
    k_transcvt<<<dim3(D_DIM / 32, D_DIM / 32), dim3(32, 8), 0, stream>>>(Whh, WhhT, D_DIM, D_DIM);
    k_transcvt<<<dim3(D_DIM / 32, 2 * D_DIM / 32), dim3(32, 8), 0, stream>>>(W1, W1T, 2 * D_DIM, D_DIM);
    k_transcvt<<<dim3(R_RULES / 32, D_DIM / 32), dim3(32, 8), 0, stream>>>(W2, Wt2, D_DIM, R_RULES);

    // Phase 4: 64 sequential RNN steps (in-place on XE)
    for (int t = 0; t < L_SEQ; ++t) {
        const bf16_t* Abase = (t == 0) ? h0b : (XE + (size_t)(t - 1) * D_DIM);
        int strideRow       = (t == 0) ? 0   : L_SEQ * D_DIM;
        k_step_mfma<<<dim3(B_BATCH / 64, D_DIM / 64), 256, 0, stream>>>(
            Abase, strideRow, WhhT, XE, t);
    }

    // Phase 5: MLP + fused rule-dot partials
    k_mlp_mfma<<<4096, 256, 0, stream>>>(
        i_idx, j_idx, XE, W1T, b1, Wt2, r_idx, par);

    // Phase 6: deterministic reduce + b2
    k_reduce<<<M_NODES / 256, 256, 0, stream>>>(par, r_idx, b2, out);
}